// Round 1
// baseline (812.776 us; speedup 1.0000x reference)
//
#include <hip/hip_runtime.h>
#include <math.h>

#define B_PTS   262144
#define NLEV    16
#define MASK4   ((1u << 22) - 1u)
#define MASK3   ((1u << 15) - 1u)
#define PRIME1  2654435761u
#define PRIME2  805459861u
#define PRIME3  3674653429u

struct LevelParams {
    float res[NLEV];
    float rest[NLEV];
};

__global__ __launch_bounds__(256)
void DoubleHashEmbedder_kernel(const float4* __restrict__ x,
                               const float2* __restrict__ emb4d,
                               const float2* __restrict__ emb3d,
                               float* __restrict__ out,
                               float* __restrict__ keep,
                               LevelParams lp)
{
    const int p   = blockIdx.x * 256 + threadIdx.x;
    const int lev = blockIdx.y;

    const float4 xv = x[p];

    const float R  = lp.res[lev];
    const float Rt = lp.rest[lev];

    float xd[4]   = { xv.x, xv.y, xv.z, xv.w };
    float resv[4] = { R, R, R, Rt };

    uint32_t t[4][2];
    float w1[4], w0[4];

    #pragma unroll
    for (int d = 0; d < 4; ++d) {
        // exact op sequence of the reference (f32 throughout)
        float grid = 1.0f / resv[d];
        float xc   = fminf(fmaxf(xd[d], 0.0f), 1.0f);
        float bl   = floorf(xc / grid);
        float vmin = bl * grid;
        float w    = (xd[d] - vmin) / grid;   // unclipped x, as in reference
        int bi     = (int)bl;
        uint32_t prime = (d == 0) ? 1u : (d == 1) ? PRIME1 : (d == 2) ? PRIME2 : PRIME3;
        t[d][0] = (uint32_t)bi * prime;
        t[d][1] = (uint32_t)(bi + 1) * prime;
        w1[d] = w;
        w0[d] = 1.0f - w;
    }

    // ---- 4D level: 16 corner gathers, all issued before use (MLP) ----
    const float2* tab4 = emb4d + ((size_t)lev << 22);
    float2 v4[16];
    #pragma unroll
    for (int c = 0; c < 16; ++c) {
        int i = (c >> 3) & 1, j = (c >> 2) & 1, k = (c >> 1) & 1, l = c & 1;
        uint32_t h = (t[0][i] ^ t[1][j] ^ t[2][k] ^ t[3][l]) & MASK4;
        v4[c] = tab4[h];
    }

    // ---- 3D level: 8 corner gathers ----
    const float2* tab3 = emb3d + ((size_t)lev << 15);
    float2 v3[8];
    #pragma unroll
    for (int c = 0; c < 8; ++c) {
        int i = (c >> 2) & 1, j = (c >> 1) & 1, k = c & 1;
        uint32_t h = (t[0][i] ^ t[1][j] ^ t[2][k]) & MASK3;
        v3[c] = tab3[h];
    }

    // ---- weighted accumulation (multilinear weights) ----
    float ex = 0.0f, ey = 0.0f;
    #pragma unroll
    for (int c = 0; c < 16; ++c) {
        int i = (c >> 3) & 1, j = (c >> 2) & 1, k = (c >> 1) & 1, l = c & 1;
        float wt = (i ? w1[0] : w0[0]) * (j ? w1[1] : w0[1]) *
                   (k ? w1[2] : w0[2]) * (l ? w1[3] : w0[3]);
        ex = fmaf(v4[c].x, wt, ex);
        ey = fmaf(v4[c].y, wt, ey);
    }
    #pragma unroll
    for (int c = 0; c < 8; ++c) {
        int i = (c >> 2) & 1, j = (c >> 1) & 1, k = c & 1;
        float wt = (i ? w1[0] : w0[0]) * (j ? w1[1] : w0[1]) *
                   (k ? w1[2] : w0[2]);
        ex = fmaf(v3[c].x, wt, ex);
        ey = fmaf(v3[c].y, wt, ey);
    }

    // embedded[p, 2*lev : 2*lev+2]  (8B-aligned float2 store)
    *reinterpret_cast<float2*>(out + (size_t)p * 32 + 2 * lev) = make_float2(ex, ey);

    if (lev == 0) {
        bool k4 = (xv.x >= 0.0f) && (xv.x <= 1.0f) &&
                  (xv.y >= 0.0f) && (xv.y <= 1.0f) &&
                  (xv.z >= 0.0f) && (xv.z <= 1.0f) &&
                  (xv.w >= 0.0f) && (xv.w <= 1.0f);
        keep[p] = k4 ? 1.0f : 0.0f;
    }
}

extern "C" void kernel_launch(void* const* d_in, const int* in_sizes, int n_in,
                              void* d_out, int out_size, void* d_ws, size_t ws_size,
                              hipStream_t stream)
{
    const float* x     = (const float*)d_in[0];
    const float* emb4d = (const float*)d_in[1];
    const float* emb3d = (const float*)d_in[2];
    float* out  = (float*)d_out;
    float* keep = out + (size_t)B_PTS * 32;

    // Replicate numpy's double-precision level-resolution computation exactly
    // (values sit on floor() boundaries: 16*b^3 ~= 32.0, 2*bt^15 ~= 32.0).
    LevelParams lp;
    const double b  = exp((log(512.0) - log(16.0)) / 15.0);
    const double bt = exp((log(32.0)  - log(2.0))  / 15.0);
    for (int i = 0; i < NLEV; ++i) {
        lp.res[i]  = (float)floor(16.0 * pow(b,  (double)i));
        lp.rest[i] = (float)floor(2.0  * pow(bt, (double)i));
    }

    dim3 grid(B_PTS / 256, NLEV);
    DoubleHashEmbedder_kernel<<<grid, 256, 0, stream>>>(
        (const float4*)x, (const float2*)emb4d, (const float2*)emb3d,
        out, keep, lp);
}

// Round 2
// 755.769 us; speedup vs baseline: 1.0754x; 1.0754x over previous
//
#include <hip/hip_runtime.h>
#include <math.h>

#define B_PTS   262144
#define NLEV    16
#define MASK4   ((1u << 22) - 1u)
#define MASK3   ((1u << 15) - 1u)
#define P1      2654435761u
#define P2      805459861u
#define P3      3674653429u
#define SHARD_SHIFT 19   // 8 shards over the 22-bit 4D hash space (4.2 MB slices)

struct LevelParams {
    float res[NLEV];
    float rest[NLEV];
};

__global__ __launch_bounds__(256, 4)
void DoubleHashEmbedder_kernel(const float4* __restrict__ x,
                               const float2* __restrict__ emb4d,
                               const float2* __restrict__ emb3d,
                               float* __restrict__ out,
                               float* __restrict__ keep,
                               LevelParams lp)
{
    // [256][33] padded: write addr = t*33 + c -> bank (t + c) & 31, conflict-free
    __shared__ float lds[256 * 33];

    const int t = threadIdx.x;
    const int p = blockIdx.x * 256 + t;

    const float4 xv = x[p];
    const float xd[4] = { xv.x, xv.y, xv.z, xv.w };

    for (int lev = 0; lev < NLEV; ++lev) {
        const float R  = lp.res[lev];
        const float Rt = lp.rest[lev];
        const float resv[4] = { R, R, R, Rt };

        uint32_t tt[4][2];
        float w0[4], w1[4];
        #pragma unroll
        for (int d = 0; d < 4; ++d) {
            // exact op sequence of the reference (f32 throughout)
            float grid = 1.0f / resv[d];
            float xc   = fminf(fmaxf(xd[d], 0.0f), 1.0f);
            float bl   = floorf(xc / grid);
            float vmin = bl * grid;
            float w    = (xd[d] - vmin) / grid;
            int bi     = (int)bl;
            uint32_t prime = (d == 0) ? 1u : (d == 1) ? P1 : (d == 2) ? P2 : P3;
            tt[d][0] = (uint32_t)bi * prime;
            tt[d][1] = (uint32_t)(bi + 1) * prime;
            w1[d] = w;
            w0[d] = 1.0f - w;
        }

        float ex = 0.0f, ey = 0.0f;

        // ---- 3D level (tables total 4 MB across levels -> cache-resident) ----
        {
            const float2* tab3 = emb3d + ((size_t)lev << 15);
            float2 v3[8];
            #pragma unroll
            for (int c = 0; c < 8; ++c) {
                uint32_t h = (tt[0][(c >> 2) & 1] ^ tt[1][(c >> 1) & 1] ^ tt[2][c & 1]) & MASK3;
                v3[c] = tab3[h];
            }
            #pragma unroll
            for (int c = 0; c < 8; ++c) {
                float wt = ((c & 4) ? w1[0] : w0[0]) *
                           ((c & 2) ? w1[1] : w0[1]) *
                           ((c & 1) ? w1[2] : w0[2]);
                ex = fmaf(v3[c].x, wt, ex);
                ey = fmaf(v3[c].y, wt, ey);
            }
        }

        // ---- 4D level ----
        {
            const float2* tab4 = emb4d + ((size_t)lev << 22);
            uint32_t h4[16];
            #pragma unroll
            for (int c = 0; c < 16; ++c)
                h4[c] = (tt[0][(c >> 3) & 1] ^ tt[1][(c >> 2) & 1] ^
                         tt[2][(c >> 1) & 1] ^ tt[3][c & 1]) & MASK4;

            if (lev < 3) {
                // small footprint: batched gathers, max MLP
                float2 v4[16];
                #pragma unroll
                for (int c = 0; c < 16; ++c) v4[c] = tab4[h4[c]];
                #pragma unroll
                for (int c = 0; c < 16; ++c) {
                    float wt = ((c & 8) ? w1[0] : w0[0]) *
                               ((c & 4) ? w1[1] : w0[1]) *
                               ((c & 2) ? w1[2] : w0[2]) *
                               ((c & 1) ? w1[3] : w0[3]);
                    ex = fmaf(v4[c].x, wt, ex);
                    ey = fmaf(v4[c].y, wt, ey);
                }
            } else {
                // large footprint: 8 shard passes so the active table slice
                // (4.2 MB) is cache-resident and line reuse is captured
                for (int s = 0; s < 8; ++s) {
                    #pragma unroll
                    for (int c = 0; c < 16; ++c) {
                        if ((h4[c] >> SHARD_SHIFT) == (uint32_t)s) {
                            float2 v = tab4[h4[c]];
                            float wt = ((c & 8) ? w1[0] : w0[0]) *
                                       ((c & 4) ? w1[1] : w0[1]) *
                                       ((c & 2) ? w1[2] : w0[2]) *
                                       ((c & 1) ? w1[3] : w0[3]);
                            ex = fmaf(v.x, wt, ex);
                            ey = fmaf(v.y, wt, ey);
                        }
                    }
                }
            }
        }

        lds[t * 33 + 2 * lev]     = ex;
        lds[t * 33 + 2 * lev + 1] = ey;
    }

    __syncthreads();

    // coalesced write-out: consecutive lanes -> consecutive 4B words
    float* ob = out + (size_t)blockIdx.x * (256 * 32);
    #pragma unroll
    for (int k = 0; k < 32; ++k) {
        int idx = k * 256 + t;
        ob[idx] = lds[(idx >> 5) * 33 + (idx & 31)];
    }

    bool k4 = (xv.x >= 0.0f) && (xv.x <= 1.0f) &&
              (xv.y >= 0.0f) && (xv.y <= 1.0f) &&
              (xv.z >= 0.0f) && (xv.z <= 1.0f) &&
              (xv.w >= 0.0f) && (xv.w <= 1.0f);
    keep[p] = k4 ? 1.0f : 0.0f;
}

extern "C" void kernel_launch(void* const* d_in, const int* in_sizes, int n_in,
                              void* d_out, int out_size, void* d_ws, size_t ws_size,
                              hipStream_t stream)
{
    const float* x     = (const float*)d_in[0];
    const float* emb4d = (const float*)d_in[1];
    const float* emb3d = (const float*)d_in[2];
    float* out  = (float*)d_out;
    float* keep = out + (size_t)B_PTS * 32;

    // Replicate numpy's double-precision level-resolution computation exactly
    // (values sit on floor() boundaries: 16*b^3 ~= 32.0, 2*bt^15 ~= 32.0).
    LevelParams lp;
    const double b  = exp((log(512.0) - log(16.0)) / 15.0);
    const double bt = exp((log(32.0)  - log(2.0))  / 15.0);
    for (int i = 0; i < NLEV; ++i) {
        lp.res[i]  = (float)floor(16.0 * pow(b,  (double)i));
        lp.rest[i] = (float)floor(2.0  * pow(bt, (double)i));
    }

    dim3 grid(B_PTS / 256, 1);
    DoubleHashEmbedder_kernel<<<grid, 256, 0, stream>>>(
        (const float4*)x, (const float2*)emb4d, (const float2*)emb3d,
        out, keep, lp);
}